// Round 6
// baseline (778.158 us; speedup 1.0000x reference)
//
#include <hip/hip_runtime.h>

typedef unsigned short u16;
typedef __attribute__((ext_vector_type(8))) short s16x8;
typedef __attribute__((ext_vector_type(4))) float f32x4;
typedef __attribute__((ext_vector_type(4))) unsigned u32x4;

#define N_CLLN 120000
#define B_CLLN 200
#define NPG    600
#define E_CLLN 1200000
#define N_MOLN 64
#define E_MOLN 256
#define N_BION 19000
#define E_BION 600000
#define HDIM   200
#define HPAD   256   // padded row stride (512 B)
#define NT     13    // 13*16 = 208 >= 200 output cols

__device__ __forceinline__ float b2f(u16 u){ return __uint_as_float(((unsigned)u)<<16); }
__device__ __forceinline__ float u2f_lo(unsigned u){ return __uint_as_float(u<<16); }
__device__ __forceinline__ float u2f_hi(unsigned u){ return __uint_as_float(u & 0xFFFF0000u); }
__device__ __forceinline__ u16 f2b(float f){
  unsigned x = __float_as_uint(f);
  return (u16)((x + 0x7fffu + ((x>>16)&1u)) >> 16);
}

// ================= CSR build =================
__global__ void hist_kernel(const int* __restrict__ dst, int* __restrict__ cnt, int E){
  int i = blockIdx.x*blockDim.x + threadIdx.x;
  if (i < E) atomicAdd(&cnt[dst[i]], 1);
}
__global__ void make_dinv(const int* __restrict__ cnt, float* __restrict__ dinv, int N){
  int i = blockIdx.x*blockDim.x + threadIdx.x;
  if (i < N) dinv[i] = rsqrtf((float)cnt[i] + 1.0f);   // +1 self loop
}
__global__ void scan1(const int* __restrict__ cnt, int* __restrict__ rows,
                      int* __restrict__ bsum, int N){
  __shared__ int sh[256];
  int b = blockIdx.x, t = threadIdx.x;
  int base = b*1024 + t*4;
  int v[4]; int s = 0;
#pragma unroll
  for (int i=0;i<4;i++){ int idx = base+i; v[i] = (idx<N)?cnt[idx]:0; s += v[i]; }
  sh[t] = s; __syncthreads();
  for (int off=1; off<256; off<<=1){
    int x = (t>=off)? sh[t-off] : 0; __syncthreads();
    sh[t] += x; __syncthreads();
  }
  int run = (t==0)? 0 : sh[t-1];
#pragma unroll
  for (int i=0;i<4;i++){ int idx = base+i; if (idx<N) rows[idx] = run; run += v[i]; }
  if (t==255) bsum[b] = sh[255];
}
__global__ void scan2(int* __restrict__ bsum, int nb){
  __shared__ int sh[256];
  int t = threadIdx.x;
  sh[t] = (t<nb)? bsum[t] : 0; __syncthreads();
  for (int off=1; off<256; off<<=1){
    int x = (t>=off)? sh[t-off] : 0; __syncthreads();
    sh[t] += x; __syncthreads();
  }
  if (t<nb) bsum[t] = (t==0)? 0 : sh[t-1];
}
__global__ void scan3(int* __restrict__ rows, const int* __restrict__ bsum, int N){
  int i = blockIdx.x*blockDim.x + threadIdx.x;
  if (i<N) rows[i] += bsum[i>>10];
}
__global__ void csr_scatter(const int* __restrict__ src, const int* __restrict__ dst,
                            const int* __restrict__ rows, int* __restrict__ cur,
                            int* __restrict__ csr, int E){
  int e = blockIdx.x*blockDim.x + threadIdx.x;
  if (e >= E) return;
  int d = dst[e];
  int p = atomicAdd(&cur[d], 1);
  csr[rows[d] + p] = src[e];
}

// ===== prescale: X'[r] = dinv[r]*X[r], fp32[ N,128 ] -> bf16[ N,128 ] =====
__global__ void prescale128(const float* __restrict__ x, const float* __restrict__ dinv,
                            u16* __restrict__ out, int N){
  int idx = blockIdx.x*blockDim.x + threadIdx.x;
  if (idx >= N*16) return;
  int r = idx >> 4, c8 = (idx & 15) << 3;
  float dv = dinv[r];
  const float* p = x + (size_t)r*128 + c8;
  f32x4 v0 = *(const f32x4*)p;
  f32x4 v1 = *(const f32x4*)(p+4);
  u32x4 w;
  w[0] = (unsigned)f2b(v0[0]*dv) | ((unsigned)f2b(v0[1]*dv)<<16);
  w[1] = (unsigned)f2b(v0[2]*dv) | ((unsigned)f2b(v0[3]*dv)<<16);
  w[2] = (unsigned)f2b(v1[0]*dv) | ((unsigned)f2b(v1[1]*dv)<<16);
  w[3] = (unsigned)f2b(v1[2]*dv) | ((unsigned)f2b(v1[3]*dv)<<16);
  *(u32x4*)(out + (size_t)r*128 + c8) = w;
}

// ===== gather over 128-col bf16 rows (256B): Y[d] = dinv[d]*(X'[d] + sum X'[s]) =====
__global__ __launch_bounds__(256) void gather128(
    const u16* __restrict__ X, const float* __restrict__ dinv,
    const int* __restrict__ rows, const int* __restrict__ csr,
    u16* __restrict__ Y, int N, int E)
{
  int wid = (blockIdx.x*blockDim.x + threadIdx.x) >> 6;
  int l = threadIdx.x & 63;
  if (wid >= N) return;
  float dv = dinv[wid];
  int e0 = rows[wid];
  int e1 = (wid+1 < N) ? rows[wid+1] : E;
  const unsigned* base = (const unsigned*)X;
  unsigned sv = base[(size_t)wid*64 + l];
  float a0 = u2f_lo(sv), a1 = u2f_hi(sv);
  for (int b0 = e0; b0 < e1; b0 += 64){
    int n = e1 - b0;
    int cnt = n < 64 ? n : 64;
    int myv = (l < cnt) ? csr[b0 + l] : 0;
    int i = 0;
    for (; i+7 < cnt; i += 8){
      int ss[8]; unsigned xs[8];
#pragma unroll
      for (int u=0;u<8;u++) ss[u] = __shfl(myv, i+u);
#pragma unroll
      for (int u=0;u<8;u++) xs[u] = base[(size_t)ss[u]*64 + l];
#pragma unroll
      for (int u=0;u<8;u++){ a0 += u2f_lo(xs[u]); a1 += u2f_hi(xs[u]); }
    }
    for (; i < cnt; ++i){
      int s0 = __shfl(myv, i);
      unsigned x0 = base[(size_t)s0*64 + l];
      a0 += u2f_lo(x0); a1 += u2f_hi(x0);
    }
  }
  ((unsigned*)Y)[(size_t)wid*64 + l] =
      (unsigned)f2b(a0*dv) | ((unsigned)f2b(a1*dv) << 16);
}

// ===== gather over padded 256-col bf16 rows (512B): Y[d] = dinv[d]*(H[d] + sum H[s]) =====
__global__ __launch_bounds__(256) void gather256(
    const u16* __restrict__ t, const float* __restrict__ dinv,
    const int* __restrict__ rows, const int* __restrict__ csr,
    u16* __restrict__ out, int N, int E)
{
  int wid = (blockIdx.x*blockDim.x + threadIdx.x) >> 6;
  int l = threadIdx.x & 63;
  if (wid >= N) return;
  float dv = dinv[wid];
  int e0 = rows[wid];
  int e1 = (wid+1 < N) ? rows[wid+1] : E;
  const unsigned* base = (const unsigned*)t;
  const unsigned* sp = base + (size_t)wid*128 + l*2;
  unsigned sx = sp[0], sy = sp[1];
  float a0 = u2f_lo(sx), a1 = u2f_hi(sx), a2 = u2f_lo(sy), a3 = u2f_hi(sy);
  for (int b0 = e0; b0 < e1; b0 += 64){
    int n = e1 - b0;
    int cnt = n < 64 ? n : 64;
    int myv = (l < cnt) ? csr[b0 + l] : 0;
    int i = 0;
    for (; i+7 < cnt; i += 8){
      int ss[8]; unsigned xs[8], ys[8];
#pragma unroll
      for (int u=0;u<8;u++) ss[u] = __shfl(myv, i+u);
#pragma unroll
      for (int u=0;u<8;u++){
        const unsigned* p = base + (size_t)ss[u]*128 + l*2;
        xs[u] = p[0]; ys[u] = p[1];
      }
#pragma unroll
      for (int u=0;u<8;u++){
        a0 += u2f_lo(xs[u]); a1 += u2f_hi(xs[u]);
        a2 += u2f_lo(ys[u]); a3 += u2f_hi(ys[u]);
      }
    }
    for (; i < cnt; ++i){
      int s0 = __shfl(myv, i);
      const unsigned* p = base + (size_t)s0*128 + l*2;
      unsigned x0 = p[0], y0 = p[1];
      a0 += u2f_lo(x0); a1 += u2f_hi(x0); a2 += u2f_lo(y0); a3 += u2f_hi(y0);
    }
  }
  unsigned rx = 0, ry = 0;
  if (l < 50){   // cols 4l..4l+3 < 200
    rx = (unsigned)f2b(a0*dv) | ((unsigned)f2b(a1*dv) << 16);
    ry = (unsigned)f2b(a2*dv) | ((unsigned)f2b(a3*dv) << 16);
  }
  unsigned* op = (unsigned*)out + (size_t)wid*128 + l*2;
  op[0] = rx; op[1] = ry;
}

// ================= B-operand pre-pack (fp32 W -> bf16 MFMA fragment order) =================
__global__ void pack_w(const float* __restrict__ W, u16* __restrict__ Bp, int K, int Ksteps){
  int idx = blockIdx.x*blockDim.x + threadIdx.x;
  int total = Ksteps*NT*64;
  if (idx >= total) return;
  int l  = idx & 63;
  int nt = (idx >> 6) % NT;
  int kk = idx / (64*NT);
  int n  = nt*16 + (l & 15);
  int k0 = kk*32 + (l>>4)*8;
  u16 v[8];
#pragma unroll
  for (int e=0;e<8;e++){
    int k = k0 + e;
    v[e] = (k < K && n < HDIM) ? f2b(W[(size_t)k*HDIM + n]) : (u16)0;
  }
#pragma unroll
  for (int e=0;e<8;e++) Bp[(size_t)idx*8 + e] = v[e];
}

// ===== MFMA GEMM over bf16 A.
// EPI=1: Out[r*HPAD+c] = f2b( dinv[r]*relu(acc + bias[c]) ), pad cols zeroed.
// EPI=3: pooled[r/600][c] += relu(acc + bias[c])  (LDS partials -> global atomics), no Out.
template<int EPI>
__global__ __launch_bounds__(256) void gemm_mfma(
    const u16* __restrict__ A, const u16* __restrict__ Bp,
    const float* __restrict__ bias, const float* __restrict__ dinv,
    u16* __restrict__ Out, float* __restrict__ pooled,
    int M, int Kact, int Ksteps, int Astride)
{
  __shared__ float ps[2][HDIM];
  if (EPI == 3){
    for (int i = threadIdx.x; i < 2*HDIM; i += 256) ((float*)ps)[i] = 0.f;
    __syncthreads();
  }
  const int w  = threadIdx.x >> 6;
  const int l  = threadIdx.x & 63;
  const int lm = l & 15;
  const int kg = l >> 4;
  int arow = blockIdx.x*64 + w*16 + lm;
  int rc = arow < M ? arow : 0;
  const u16* Arow = A + (size_t)rc * Astride;
  f32x4 fz = {0.f,0.f,0.f,0.f};
  f32x4 acc[NT];
#pragma unroll
  for (int t=0;t<NT;t++) acc[t] = fz;
  s16x8 az = {0,0,0,0,0,0,0,0};
  for (int kk=0; kk<Ksteps; ++kk){
    int k0 = kk*32 + kg*8;
    s16x8 a = (k0 < Kact) ? *(const s16x8*)(Arow + k0) : az;
    const u16* bp = Bp + ((size_t)kk*NT*64 + l)*8;
#pragma unroll
    for (int t=0;t<NT;t++){
      s16x8 b = *(const s16x8*)(bp + t*512);
      acc[t] = __builtin_amdgcn_mfma_f32_16x16x32_bf16(a, b, acc[t], 0, 0, 0);
    }
  }
  int orow = blockIdx.x*64 + w*16 + kg*4;   // C/D: col = lane&15, row = (lane>>4)*4 + j
  if (EPI == 1){
    float sc[4];
#pragma unroll
    for (int j=0;j<4;j++){ int r = orow + j; sc[j] = (r < M) ? dinv[r] : 0.f; }
#pragma unroll
    for (int t=0;t<NT;t++){
      int c = t*16 + lm;
#pragma unroll
      for (int j=0;j<4;j++){
        int r = orow + j;
        if (r < M){
          float v = 0.f;
          if (c < HDIM) v = fmaxf(acc[t][j] + bias[c], 0.f) * sc[j];
          Out[(size_t)r*HPAD + c] = f2b(v);
        }
      }
    }
  } else {
    int g0 = (blockIdx.x*64) / 600;
#pragma unroll
    for (int t=0;t<NT;t++){
      int c = t*16 + lm;
      if (c < HDIM){
#pragma unroll
        for (int j=0;j<4;j++){
          int r = orow + j;
          if (r < M){
            float v = fmaxf(acc[t][j] + bias[c], 0.f);
            atomicAdd(&ps[(r/600) - g0][c], v);
          }
        }
      }
    }
    __syncthreads();
    for (int i = threadIdx.x; i < 2*HDIM; i += 256){
      int gi = i / HDIM, c = i % HDIM;
      float v = ps[gi][c];
      int g = g0 + gi;
      if (g < B_CLLN && v != 0.f) unsafeAtomicAdd(&pooled[g*HDIM + c], v);
    }
  }
}

// ================= xc = pooled/NPG @ Wlc + blc =================
__global__ void xc_kernel(const float* __restrict__ pooled, const float* __restrict__ Wlc,
                          const float* __restrict__ blc, float* __restrict__ xc){
  __shared__ float p[HDIM];
  int b = blockIdx.x, j = threadIdx.x;   // 256 threads, 256 out cols
  if (j < HDIM) p[j] = pooled[b*HDIM + j] * (1.0f/NPG);
  __syncthreads();
  float s = blc[j];
  for (int k=0;k<HDIM;k++) s += p[k]*Wlc[(size_t)k*256 + j];
  xc[(size_t)b*256 + j] = s;
}

// ================= mol branch (all fp32) =================
__global__ void mol_agg(const float* __restrict__ x, const int* __restrict__ src,
                        const int* __restrict__ dst, float* __restrict__ a, int E, int F){
  int idx = blockIdx.x*blockDim.x + threadIdx.x;
  if (idx >= E*F) return;
  int e = idx / F, f = idx % F;
  unsafeAtomicAdd(&a[dst[e]*F + f], x[(size_t)src[e]*F + f]);
}
__global__ void mol_l1(const float* __restrict__ x, const float* __restrict__ a1,
                       const float* __restrict__ Wrel, const float* __restrict__ brel,
                       const float* __restrict__ Wroot, float* __restrict__ m1){
  int idx = blockIdx.x*blockDim.x + threadIdx.x;
  if (idx >= N_MOLN*HDIM) return;
  int i = idx / HDIM, c = idx % HDIM;
  float s = brel[c];
  for (int k=0;k<64;k++){
    s += a1[i*64+k]*Wrel[k*HDIM+c];
    s += x[i*64+k]*Wroot[k*HDIM+c];
  }
  m1[idx] = fmaxf(s, 0.f);
}
__global__ void mol_l2(const float* __restrict__ m1, const float* __restrict__ a2,
                       const float* __restrict__ Wrel2, const float* __restrict__ brel2,
                       const float* __restrict__ Wroot2, float* __restrict__ colsum){
  int idx = blockIdx.x*blockDim.x + threadIdx.x;
  if (idx >= N_MOLN*HDIM) return;
  int i = idx / HDIM, c = idx % HDIM;
  float s = brel2[c];
  for (int k=0;k<HDIM;k++){
    s += a2[i*HDIM+k]*Wrel2[k*HDIM+c] + m1[i*HDIM+k]*Wroot2[k*HDIM+c];
  }
  s = fmaxf(s, 0.f);
  unsafeAtomicAdd(&colsum[c], s*(1.0f/N_MOLN));
}
__global__ void mol_head(const float* __restrict__ colsum, const float* __restrict__ Wlm,
                         const float* __restrict__ blm, float* __restrict__ xm){
  int j = threadIdx.x;
  if (j >= 128) return;
  float s = blm[j];
  for (int c=0;c<HDIM;c++) s += colsum[c]*Wlm[c*128+j];
  xm[j] = s;
}

// ===== bio tail: aggregate-first for last node only, then Wb2+relu, then Wlb =====
__global__ void bio_head(const u16* __restrict__ H1, const float* __restrict__ dinv,
                         const int* __restrict__ rows, const int* __restrict__ csr,
                         const float* __restrict__ bb2, const float* __restrict__ Wb2,
                         const float* __restrict__ Wlb, const float* __restrict__ blb,
                         float* __restrict__ xb, int N, int E){
  __shared__ float Y2[HDIM];
  __shared__ float wv[HDIM];
  int last = N-1, tid = threadIdx.x;   // 256 threads
  if (tid < HDIM){
    float acc = b2f(H1[(size_t)last*HPAD + tid]);
    for (int e = rows[last]; e < E; ++e)
      acc += b2f(H1[(size_t)csr[e]*HPAD + tid]);
    Y2[tid] = acc * dinv[last];
  }
  __syncthreads();
  if (tid < HDIM){
    float s = bb2[tid];
    for (int k=0;k<HDIM;k++) s += Y2[k]*Wb2[k*HDIM + tid];
    wv[tid] = fmaxf(s, 0.f);
  }
  __syncthreads();
  if (tid < 128){
    float s = blb[tid];
    for (int c=0;c<HDIM;c++) s += wv[c]*Wlb[c*128 + tid];
    xb[tid] = s;
  }
}

// ================= bilinear score =================
__global__ void score_kernel(const float* __restrict__ xc, const float* __restrict__ W,
                             const float* __restrict__ bias, const float* __restrict__ xm,
                             const float* __restrict__ xb, float* __restrict__ out){
  __shared__ float xd[256];
  __shared__ float u[256];
  int tid = threadIdx.x;   // 256
  xd[tid] = (tid < 128) ? xm[tid] : xb[tid-128];
  __syncthreads();
  float s = 0.f;
  for (int j=0;j<256;j++) s += W[(size_t)tid*256 + j]*xd[j];
  u[tid] = s;
  __syncthreads();
  if (tid < B_CLLN){
    float sc = bias[0];
    const float* xr = xc + (size_t)tid*256;
    for (int i=0;i<256;i++) sc += xr[i]*u[i];
    out[tid] = sc;
  }
}

extern "C" void kernel_launch(void* const* d_in, const int* in_sizes, int n_in,
                              void* d_out, int out_size, void* d_ws, size_t ws_size,
                              hipStream_t stream) {
  const float* x_cll = (const float*)d_in[0];
  const float* x_mol = (const float*)d_in[1];
  const float* x_bio = (const float*)d_in[2];
  const int* e_cll = (const int*)d_in[3];
  const int* e_mol = (const int*)d_in[5];
  const int* e_bio = (const int*)d_in[6];
  const float *Wc1=(const float*)d_in[7],  *bc1=(const float*)d_in[8];
  const float *Wc2=(const float*)d_in[9],  *bc2=(const float*)d_in[10];
  const float *Wlc=(const float*)d_in[11], *blc=(const float*)d_in[12];
  const float *Wrel1=(const float*)d_in[13],*brel1=(const float*)d_in[14],*Wroot1=(const float*)d_in[15];
  const float *Wrel2=(const float*)d_in[16],*brel2=(const float*)d_in[17],*Wroot2=(const float*)d_in[18];
  const float *Wlm=(const float*)d_in[19], *blm=(const float*)d_in[20];
  const float *Wb1=(const float*)d_in[21], *bb1=(const float*)d_in[22];
  const float *Wb2=(const float*)d_in[23], *bb2=(const float*)d_in[24];
  const float *Wlb=(const float*)d_in[25], *blb=(const float*)d_in[26];
  const float *Wbl=(const float*)d_in[27], *bias=(const float*)d_in[28];
  float* out = (float*)d_out;

  char* ws = (char*)d_ws;
  size_t o = 0;
  auto alloc = [&](size_t bytes)->char*{
    char* p = ws + o;
    o = (o + bytes + 255) & ~(size_t)255;
    return p;
  };
  u16*   XS    = (u16*)  alloc((size_t)N_CLLN*128*2);    // prescaled input, 31 MB
  u16*   Y1    = (u16*)  alloc((size_t)N_CLLN*128*2);    // layer-1 aggregate, 31 MB
  u16*   BUF1  = (u16*)  alloc((size_t)N_CLLN*HPAD*2);   // H1 (padded), 61 MB
  u16*   BUF2  = (u16*)  alloc((size_t)N_CLLN*HPAD*2);   // Y2 (padded), 61 MB
  float* dinvC = (float*)alloc((size_t)N_CLLN*4);
  float* dinvB = (float*)alloc((size_t)N_BION*4);
  int*   cntC  = (int*)  alloc((size_t)(2*N_CLLN+2*N_BION)*4);  // cnt/cur zero region
  int*   curC  = cntC + N_CLLN;
  int*   cntB  = curC + N_CLLN;
  int*   curB  = cntB + N_BION;
  int*   rowC  = (int*)  alloc((size_t)N_CLLN*4);
  int*   csrC  = (int*)  alloc((size_t)E_CLLN*4);
  int*   rowB  = (int*)  alloc((size_t)N_BION*4);
  int*   csrB  = (int*)  alloc((size_t)E_BION*4);
  int*   bsumC = (int*)  alloc(256*4);
  int*   bsumB = (int*)  alloc(256*4);
  float* pooled= (float*)alloc((size_t)B_CLLN*HDIM*4);   // zeroed each launch
  float* xc    = (float*)alloc((size_t)B_CLLN*256*4);
  float* a1    = (float*)alloc((size_t)(N_MOLN*64 + N_MOLN*HDIM + HDIM)*4);  // zero region
  float* a2    = a1 + N_MOLN*64;
  float* colsum= a2 + N_MOLN*HDIM;
  float* m1    = (float*)alloc((size_t)N_MOLN*HDIM*4);
  float* xm    = (float*)alloc(128*4);
  float* xb    = (float*)alloc(128*4);
  u16* Pc1 = (u16*)alloc((size_t)4*NT*64*8*2);
  u16* Pc2 = (u16*)alloc((size_t)7*NT*64*8*2);
  u16* Pb1 = (u16*)alloc((size_t)4*NT*64*8*2);
  u16* Pb2 = (u16*)alloc((size_t)7*NT*64*8*2);
  if (o > ws_size) return;   // scratch too small; bail deterministically
  (void)in_sizes; (void)n_in; (void)out_size;

  hipMemsetAsync(cntC, 0, (size_t)(2*N_CLLN+2*N_BION)*4, stream);
  hipMemsetAsync(pooled, 0, (size_t)B_CLLN*HDIM*4, stream);
  hipMemsetAsync(a1, 0, (size_t)(N_MOLN*64 + N_MOLN*HDIM + HDIM)*4, stream);

  // pack weights
  pack_w<<<(4*NT*64+255)/256, 256, 0, stream>>>(Wc1, Pc1, 128, 4);
  pack_w<<<(7*NT*64+255)/256, 256, 0, stream>>>(Wc2, Pc2, 200, 7);
  pack_w<<<(4*NT*64+255)/256, 256, 0, stream>>>(Wb1, Pb1, 128, 4);
  pack_w<<<(7*NT*64+255)/256, 256, 0, stream>>>(Wb2, Pb2, 200, 7);

  // ---- CSR build: cll ----
  const int* srcC = e_cll;  const int* dstC = e_cll + E_CLLN;
  hist_kernel<<<(E_CLLN+255)/256, 256, 0, stream>>>(dstC, cntC, E_CLLN);
  make_dinv<<<(N_CLLN+255)/256, 256, 0, stream>>>(cntC, dinvC, N_CLLN);
  scan1<<<(N_CLLN+1023)/1024, 256, 0, stream>>>(cntC, rowC, bsumC, N_CLLN);
  scan2<<<1, 256, 0, stream>>>(bsumC, (N_CLLN+1023)/1024);
  scan3<<<(N_CLLN+255)/256, 256, 0, stream>>>(rowC, bsumC, N_CLLN);
  csr_scatter<<<(E_CLLN+255)/256, 256, 0, stream>>>(srcC, dstC, rowC, curC, csrC, E_CLLN);
  // ---- CSR build: bio ----
  const int* srcB = e_bio;  const int* dstB = e_bio + E_BION;
  hist_kernel<<<(E_BION+255)/256, 256, 0, stream>>>(dstB, cntB, E_BION);
  make_dinv<<<(N_BION+255)/256, 256, 0, stream>>>(cntB, dinvB, N_BION);
  scan1<<<(N_BION+1023)/1024, 256, 0, stream>>>(cntB, rowB, bsumB, N_BION);
  scan2<<<1, 256, 0, stream>>>(bsumB, (N_BION+1023)/1024);
  scan3<<<(N_BION+255)/256, 256, 0, stream>>>(rowB, bsumB, N_BION);
  csr_scatter<<<(E_BION+255)/256, 256, 0, stream>>>(srcB, dstB, rowB, curB, csrB, E_BION);

  const int gcll = (N_CLLN+63)/64;
  const int gbio = (N_BION+63)/64;
  const int wcll = (N_CLLN+3)/4;   // one wave per node, 4 waves/block
  const int wbio = (N_BION+3)/4;

  // ---- cll branch ----
  prescale128<<<(N_CLLN*16+255)/256, 256, 0, stream>>>(x_cll, dinvC, XS, N_CLLN);
  gather128<<<wcll, 256, 0, stream>>>(XS, dinvC, rowC, csrC, Y1, N_CLLN, E_CLLN);
  gemm_mfma<1><<<gcll, 256, 0, stream>>>(Y1, Pc1, bc1, dinvC, BUF1, nullptr,
                                         N_CLLN, 128, 4, 128);
  gather256<<<wcll, 256, 0, stream>>>(BUF1, dinvC, rowC, csrC, BUF2, N_CLLN, E_CLLN);
  gemm_mfma<3><<<gcll, 256, 0, stream>>>(BUF2, Pc2, bc2, nullptr, nullptr, pooled,
                                         N_CLLN, 200, 7, HPAD);
  xc_kernel<<<B_CLLN, 256, 0, stream>>>(pooled, Wlc, blc, xc);

  // ---- bio branch (reuses big buffers after cll is done with them) ----
  prescale128<<<(N_BION*16+255)/256, 256, 0, stream>>>(x_bio, dinvB, XS, N_BION);
  gather128<<<wbio, 256, 0, stream>>>(XS, dinvB, rowB, csrB, Y1, N_BION, E_BION);
  gemm_mfma<1><<<gbio, 256, 0, stream>>>(Y1, Pb1, bb1, dinvB, BUF1, nullptr,
                                         N_BION, 128, 4, 128);
  bio_head<<<1, 256, 0, stream>>>(BUF1, dinvB, rowB, csrB, bb2, Wb2, Wlb, blb,
                                  xb, N_BION, E_BION);

  // ---- mol branch ----
  mol_agg<<<(E_MOLN*64+255)/256, 256, 0, stream>>>(x_mol, e_mol, e_mol + E_MOLN, a1, E_MOLN, 64);
  mol_l1<<<(N_MOLN*HDIM+255)/256, 256, 0, stream>>>(x_mol, a1, Wrel1, brel1, Wroot1, m1);
  mol_agg<<<(E_MOLN*HDIM+255)/256, 256, 0, stream>>>(m1, e_mol, e_mol + E_MOLN, a2, E_MOLN, HDIM);
  mol_l2<<<(N_MOLN*HDIM+255)/256, 256, 0, stream>>>(m1, a2, Wrel2, brel2, Wroot2, colsum);
  mol_head<<<1, 128, 0, stream>>>(colsum, Wlm, blm, xm);

  // ---- score ----
  score_kernel<<<1, 256, 0, stream>>>(xc, Wbl, bias, xm, xb, out);
}

// Round 7
// 664.297 us; speedup vs baseline: 1.1714x; 1.1714x over previous
//
#include <hip/hip_runtime.h>

typedef unsigned short u16;
typedef __attribute__((ext_vector_type(8))) short s16x8;
typedef __attribute__((ext_vector_type(4))) float f32x4;
typedef __attribute__((ext_vector_type(4))) unsigned u32x4;

#define N_CLLN 120000
#define B_CLLN 200
#define NPG    600
#define E_CLLN 1200000
#define N_MOLN 64
#define E_MOLN 256
#define N_BION 19000
#define E_BION 600000
#define HDIM   200
#define HPAD   256   // padded row stride (512 B)
#define NT     13    // 13*16 = 208 >= 200 output cols

__device__ __forceinline__ float b2f(u16 u){ return __uint_as_float(((unsigned)u)<<16); }
__device__ __forceinline__ float u2f_lo(unsigned u){ return __uint_as_float(u<<16); }
__device__ __forceinline__ float u2f_hi(unsigned u){ return __uint_as_float(u & 0xFFFF0000u); }
__device__ __forceinline__ u16 f2b(float f){
  unsigned x = __float_as_uint(f);
  return (u16)((x + 0x7fffu + ((x>>16)&1u)) >> 16);
}

// ================= CSR build =================
__global__ void hist_kernel(const int* __restrict__ dst, int* __restrict__ cnt, int E){
  int i = blockIdx.x*blockDim.x + threadIdx.x;
  if (i < E) atomicAdd(&cnt[dst[i]], 1);
}
__global__ void make_dinv(const int* __restrict__ cnt, float* __restrict__ dinv, int N){
  int i = blockIdx.x*blockDim.x + threadIdx.x;
  if (i < N) dinv[i] = rsqrtf((float)cnt[i] + 1.0f);   // +1 self loop
}
__global__ void scan1(const int* __restrict__ cnt, int* __restrict__ rows,
                      int* __restrict__ bsum, int N){
  __shared__ int sh[256];
  int b = blockIdx.x, t = threadIdx.x;
  int base = b*1024 + t*4;
  int v[4]; int s = 0;
#pragma unroll
  for (int i=0;i<4;i++){ int idx = base+i; v[i] = (idx<N)?cnt[idx]:0; s += v[i]; }
  sh[t] = s; __syncthreads();
  for (int off=1; off<256; off<<=1){
    int x = (t>=off)? sh[t-off] : 0; __syncthreads();
    sh[t] += x; __syncthreads();
  }
  int run = (t==0)? 0 : sh[t-1];
#pragma unroll
  for (int i=0;i<4;i++){ int idx = base+i; if (idx<N) rows[idx] = run; run += v[i]; }
  if (t==255) bsum[b] = sh[255];
}
__global__ void scan2(int* __restrict__ bsum, int nb){
  __shared__ int sh[256];
  int t = threadIdx.x;
  sh[t] = (t<nb)? bsum[t] : 0; __syncthreads();
  for (int off=1; off<256; off<<=1){
    int x = (t>=off)? sh[t-off] : 0; __syncthreads();
    sh[t] += x; __syncthreads();
  }
  if (t<nb) bsum[t] = (t==0)? 0 : sh[t-1];
}
__global__ void scan3(int* __restrict__ rows, const int* __restrict__ bsum, int N){
  int i = blockIdx.x*blockDim.x + threadIdx.x;
  if (i<N) rows[i] += bsum[i>>10];
}
__global__ void csr_scatter(const int* __restrict__ src, const int* __restrict__ dst,
                            const int* __restrict__ rows, int* __restrict__ cur,
                            int* __restrict__ csr, int E){
  int e = blockIdx.x*blockDim.x + threadIdx.x;
  if (e >= E) return;
  int d = dst[e];
  int p = atomicAdd(&cur[d], 1);
  csr[rows[d] + p] = src[e];
}

// ===== prescale: X'[r] = dinv[r]*X[r], fp32[N,128] -> bf16[N,128] =====
__global__ void prescale128(const float* __restrict__ x, const float* __restrict__ dinv,
                            u16* __restrict__ out, int N){
  int idx = blockIdx.x*blockDim.x + threadIdx.x;
  if (idx >= N*16) return;
  int r = idx >> 4, c8 = (idx & 15) << 3;
  float dv = dinv[r];
  const float* p = x + (size_t)r*128 + c8;
  f32x4 v0 = *(const f32x4*)p;
  f32x4 v1 = *(const f32x4*)(p+4);
  u32x4 w;
  w[0] = (unsigned)f2b(v0[0]*dv) | ((unsigned)f2b(v0[1]*dv)<<16);
  w[1] = (unsigned)f2b(v0[2]*dv) | ((unsigned)f2b(v0[3]*dv)<<16);
  w[2] = (unsigned)f2b(v1[0]*dv) | ((unsigned)f2b(v1[1]*dv)<<16);
  w[3] = (unsigned)f2b(v1[2]*dv) | ((unsigned)f2b(v1[3]*dv)<<16);
  *(u32x4*)(out + (size_t)r*128 + c8) = w;
}

// ===== gather over 128-col bf16 rows (256B): Y[d] = dinv[d]*(X'[d] + sum X'[s]) =====
__global__ __launch_bounds__(256) void gather128(
    const u16* __restrict__ X, const float* __restrict__ dinv,
    const int* __restrict__ rows, const int* __restrict__ csr,
    u16* __restrict__ Y, int N, int E)
{
  int wid = (blockIdx.x*blockDim.x + threadIdx.x) >> 6;
  int l = threadIdx.x & 63;
  if (wid >= N) return;
  float dv = dinv[wid];
  int e0 = rows[wid];
  int e1 = (wid+1 < N) ? rows[wid+1] : E;
  const unsigned* base = (const unsigned*)X;
  unsigned sv = base[(size_t)wid*64 + l];
  float a0 = u2f_lo(sv), a1 = u2f_hi(sv);
  for (int b0 = e0; b0 < e1; b0 += 64){
    int n = e1 - b0;
    int cnt = n < 64 ? n : 64;
    int myv = (l < cnt) ? csr[b0 + l] : 0;
    int i = 0;
    for (; i+7 < cnt; i += 8){
      int ss[8]; unsigned xs[8];
#pragma unroll
      for (int u=0;u<8;u++) ss[u] = __shfl(myv, i+u);
#pragma unroll
      for (int u=0;u<8;u++) xs[u] = base[(size_t)ss[u]*64 + l];
#pragma unroll
      for (int u=0;u<8;u++){ a0 += u2f_lo(xs[u]); a1 += u2f_hi(xs[u]); }
    }
    for (; i < cnt; ++i){
      int s0 = __shfl(myv, i);
      unsigned x0 = base[(size_t)s0*64 + l];
      a0 += u2f_lo(x0); a1 += u2f_hi(x0);
    }
  }
  ((unsigned*)Y)[(size_t)wid*64 + l] =
      (unsigned)f2b(a0*dv) | ((unsigned)f2b(a1*dv) << 16);
}

// ===== gather over padded 256-col bf16 rows (512B) =====
__global__ __launch_bounds__(256) void gather256(
    const u16* __restrict__ t, const float* __restrict__ dinv,
    const int* __restrict__ rows, const int* __restrict__ csr,
    u16* __restrict__ out, int N, int E)
{
  int wid = (blockIdx.x*blockDim.x + threadIdx.x) >> 6;
  int l = threadIdx.x & 63;
  if (wid >= N) return;
  float dv = dinv[wid];
  int e0 = rows[wid];
  int e1 = (wid+1 < N) ? rows[wid+1] : E;
  const unsigned* base = (const unsigned*)t;
  const unsigned* sp = base + (size_t)wid*128 + l*2;
  unsigned sx = sp[0], sy = sp[1];
  float a0 = u2f_lo(sx), a1 = u2f_hi(sx), a2 = u2f_lo(sy), a3 = u2f_hi(sy);
  for (int b0 = e0; b0 < e1; b0 += 64){
    int n = e1 - b0;
    int cnt = n < 64 ? n : 64;
    int myv = (l < cnt) ? csr[b0 + l] : 0;
    int i = 0;
    for (; i+7 < cnt; i += 8){
      int ss[8]; unsigned xs[8], ys[8];
#pragma unroll
      for (int u=0;u<8;u++) ss[u] = __shfl(myv, i+u);
#pragma unroll
      for (int u=0;u<8;u++){
        const unsigned* p = base + (size_t)ss[u]*128 + l*2;
        xs[u] = p[0]; ys[u] = p[1];
      }
#pragma unroll
      for (int u=0;u<8;u++){
        a0 += u2f_lo(xs[u]); a1 += u2f_hi(xs[u]);
        a2 += u2f_lo(ys[u]); a3 += u2f_hi(ys[u]);
      }
    }
    for (; i < cnt; ++i){
      int s0 = __shfl(myv, i);
      const unsigned* p = base + (size_t)s0*128 + l*2;
      unsigned x0 = p[0], y0 = p[1];
      a0 += u2f_lo(x0); a1 += u2f_hi(x0); a2 += u2f_lo(y0); a3 += u2f_hi(y0);
    }
  }
  unsigned rx = 0, ry = 0;
  if (l < 50){
    rx = (unsigned)f2b(a0*dv) | ((unsigned)f2b(a1*dv) << 16);
    ry = (unsigned)f2b(a2*dv) | ((unsigned)f2b(a3*dv) << 16);
  }
  unsigned* op = (unsigned*)out + (size_t)wid*128 + l*2;
  op[0] = rx; op[1] = ry;
}

// ================= B-operand pre-pack (fp32 W -> bf16 MFMA fragment order) =================
__global__ void pack_w(const float* __restrict__ W, u16* __restrict__ Bp, int K, int Ksteps){
  int idx = blockIdx.x*blockDim.x + threadIdx.x;
  int total = Ksteps*NT*64;
  if (idx >= total) return;
  int l  = idx & 63;
  int nt = (idx >> 6) % NT;
  int kk = idx / (64*NT);
  int n  = nt*16 + (l & 15);
  int k0 = kk*32 + (l>>4)*8;
  u16 v[8];
#pragma unroll
  for (int e=0;e<8;e++){
    int k = k0 + e;
    v[e] = (k < K && n < HDIM) ? f2b(W[(size_t)k*HDIM + n]) : (u16)0;
  }
#pragma unroll
  for (int e=0;e<8;e++) Bp[(size_t)idx*8 + e] = v[e];
}

// ===== GEMM core: 128 rows/block, 4 waves, 2 A-frags per wave, compile-time K =====
// Out[r*HPAD+c] = f2b( dinv[r] * relu(acc + bias[c]) ), c in [0,208), pad-cols 200..207 zero.
template<int KSTEPS, int KACT>
__global__ __launch_bounds__(256) void gemm_h1(
    const u16* __restrict__ A, const u16* __restrict__ Bp,
    const float* __restrict__ bias, const float* __restrict__ dinv,
    u16* __restrict__ Out, int M, int Astride)
{
  const int w  = threadIdx.x >> 6;
  const int l  = threadIdx.x & 63;
  const int lm = l & 15;
  const int kg = l >> 4;
  const int base = blockIdx.x*128;
  int r0 = base + w*16 + lm;
  int r1 = r0 + 64;
  const u16* A0 = A + (size_t)(r0 < M ? r0 : 0) * Astride;
  const u16* A1 = A + (size_t)(r1 < M ? r1 : 0) * Astride;
  f32x4 acc[2][NT] = {};
  const s16x8 az = {0,0,0,0,0,0,0,0};
#pragma unroll
  for (int kk=0; kk<KSTEPS; ++kk){
    int k0 = kk*32 + kg*8;
    s16x8 a0 = (k0 < KACT) ? *(const s16x8*)(A0 + k0) : az;
    s16x8 a1 = (k0 < KACT) ? *(const s16x8*)(A1 + k0) : az;
    const u16* bp = Bp + ((size_t)kk*NT*64 + l)*8;
#pragma unroll
    for (int t=0;t<NT;t++){
      s16x8 b = *(const s16x8*)(bp + t*512);
      acc[0][t] = __builtin_amdgcn_mfma_f32_16x16x32_bf16(a0, b, acc[0][t], 0, 0, 0);
      acc[1][t] = __builtin_amdgcn_mfma_f32_16x16x32_bf16(a1, b, acc[1][t], 0, 0, 0);
    }
  }
#pragma unroll
  for (int m=0;m<2;m++){
    int orow = base + m*64 + w*16 + kg*4;   // C/D: col=lane&15, row=(lane>>4)*4+j
    float scj[4];
#pragma unroll
    for (int j=0;j<4;j++){ int r = orow + j; scj[j] = (r < M) ? dinv[r] : 0.f; }
#pragma unroll
    for (int t=0;t<NT;t++){
      int c = t*16 + lm;
#pragma unroll
      for (int j=0;j<4;j++){
        int r = orow + j;
        if (r < M){
          float v = 0.f;
          if (c < HDIM) v = fmaxf(acc[m][t][j] + bias[c], 0.f) * scj[j];
          Out[(size_t)r*HPAD + c] = f2b(v);
        }
      }
    }
  }
}

// ===== GEMM + fused mean-pool epilogue (no LDS, shfl reduce + global f32 atomics) =====
template<int KSTEPS, int KACT>
__global__ __launch_bounds__(256) void gemm_pool(
    const u16* __restrict__ A, const u16* __restrict__ Bp,
    const float* __restrict__ bias, float* __restrict__ pooled,
    int M, int Astride)
{
  const int w  = threadIdx.x >> 6;
  const int l  = threadIdx.x & 63;
  const int lm = l & 15;
  const int kg = l >> 4;
  const int base = blockIdx.x*128;
  int r0 = base + w*16 + lm;
  int r1 = r0 + 64;
  const u16* A0 = A + (size_t)(r0 < M ? r0 : 0) * Astride;
  const u16* A1 = A + (size_t)(r1 < M ? r1 : 0) * Astride;
  f32x4 acc[2][NT] = {};
  const s16x8 az = {0,0,0,0,0,0,0,0};
#pragma unroll
  for (int kk=0; kk<KSTEPS; ++kk){
    int k0 = kk*32 + kg*8;
    s16x8 a0 = (k0 < KACT) ? *(const s16x8*)(A0 + k0) : az;
    s16x8 a1 = (k0 < KACT) ? *(const s16x8*)(A1 + k0) : az;
    const u16* bp = Bp + ((size_t)kk*NT*64 + l)*8;
#pragma unroll
    for (int t=0;t<NT;t++){
      s16x8 b = *(const s16x8*)(bp + t*512);
      acc[0][t] = __builtin_amdgcn_mfma_f32_16x16x32_bf16(a0, b, acc[0][t], 0, 0, 0);
      acc[1][t] = __builtin_amdgcn_mfma_f32_16x16x32_bf16(a1, b, acc[1][t], 0, 0, 0);
    }
  }
#pragma unroll
  for (int m=0;m<2;m++){
    int R0 = base + m*64 + w*16;   // wave-uniform frag start
    bool fast = (R0 + 15 < M) && ((R0/NPG) == ((R0+15)/NPG));
#pragma unroll
    for (int t=0;t<NT;t++){
      int c = t*16 + lm;
      if (c < HDIM){
        float v0 = fmaxf(acc[m][t][0] + bias[c], 0.f);
        float v1 = fmaxf(acc[m][t][1] + bias[c], 0.f);
        float v2 = fmaxf(acc[m][t][2] + bias[c], 0.f);
        float v3 = fmaxf(acc[m][t][3] + bias[c], 0.f);
        if (fast){
          float s = v0+v1+v2+v3;
          s += __shfl_xor(s, 16);
          s += __shfl_xor(s, 32);
          if (kg == 0) unsafeAtomicAdd(&pooled[(R0/NPG)*HDIM + c], s);
        } else {
          float vv0 = v0, vv1 = v1, vv2 = v2, vv3 = v3;
          int rb = R0 + kg*4;
          if (rb   < M) unsafeAtomicAdd(&pooled[((rb  )/NPG)*HDIM + c], vv0);
          if (rb+1 < M) unsafeAtomicAdd(&pooled[((rb+1)/NPG)*HDIM + c], vv1);
          if (rb+2 < M) unsafeAtomicAdd(&pooled[((rb+2)/NPG)*HDIM + c], vv2);
          if (rb+3 < M) unsafeAtomicAdd(&pooled[((rb+3)/NPG)*HDIM + c], vv3);
        }
      }
    }
  }
}

// ================= xc = pooled/NPG @ Wlc + blc =================
__global__ void xc_kernel(const float* __restrict__ pooled, const float* __restrict__ Wlc,
                          const float* __restrict__ blc, float* __restrict__ xc){
  __shared__ float p[HDIM];
  int b = blockIdx.x, j = threadIdx.x;
  if (j < HDIM) p[j] = pooled[b*HDIM + j] * (1.0f/NPG);
  __syncthreads();
  float s = blc[j];
  for (int k=0;k<HDIM;k++) s += p[k]*Wlc[(size_t)k*256 + j];
  xc[(size_t)b*256 + j] = s;
}

// ================= mol branch (all fp32) =================
__global__ void mol_agg(const float* __restrict__ x, const int* __restrict__ src,
                        const int* __restrict__ dst, float* __restrict__ a, int E, int F){
  int idx = blockIdx.x*blockDim.x + threadIdx.x;
  if (idx >= E*F) return;
  int e = idx / F, f = idx % F;
  unsafeAtomicAdd(&a[dst[e]*F + f], x[(size_t)src[e]*F + f]);
}
__global__ void mol_l1(const float* __restrict__ x, const float* __restrict__ a1,
                       const float* __restrict__ Wrel, const float* __restrict__ brel,
                       const float* __restrict__ Wroot, float* __restrict__ m1){
  int idx = blockIdx.x*blockDim.x + threadIdx.x;
  if (idx >= N_MOLN*HDIM) return;
  int i = idx / HDIM, c = idx % HDIM;
  float s = brel[c];
  for (int k=0;k<64;k++){
    s += a1[i*64+k]*Wrel[k*HDIM+c];
    s += x[i*64+k]*Wroot[k*HDIM+c];
  }
  m1[idx] = fmaxf(s, 0.f);
}
__global__ void mol_l2(const float* __restrict__ m1, const float* __restrict__ a2,
                       const float* __restrict__ Wrel2, const float* __restrict__ brel2,
                       const float* __restrict__ Wroot2, float* __restrict__ colsum){
  int idx = blockIdx.x*blockDim.x + threadIdx.x;
  if (idx >= N_MOLN*HDIM) return;
  int i = idx / HDIM, c = idx % HDIM;
  float s = brel2[c];
  for (int k=0;k<HDIM;k++){
    s += a2[i*HDIM+k]*Wrel2[k*HDIM+c] + m1[i*HDIM+k]*Wroot2[k*HDIM+c];
  }
  s = fmaxf(s, 0.f);
  unsafeAtomicAdd(&colsum[c], s*(1.0f/N_MOLN));
}
__global__ void mol_head(const float* __restrict__ colsum, const float* __restrict__ Wlm,
                         const float* __restrict__ blm, float* __restrict__ xm){
  int j = threadIdx.x;
  if (j >= 128) return;
  float s = blm[j];
  for (int c=0;c<HDIM;c++) s += colsum[c]*Wlm[c*128+j];
  xm[j] = s;
}

// ===== bio tail: aggregate-first for last node only, then Wb2+relu, then Wlb =====
__global__ void bio_head(const u16* __restrict__ H1, const float* __restrict__ dinv,
                         const int* __restrict__ rows, const int* __restrict__ csr,
                         const float* __restrict__ bb2, const float* __restrict__ Wb2,
                         const float* __restrict__ Wlb, const float* __restrict__ blb,
                         float* __restrict__ xb, int N, int E){
  __shared__ float Y2[HDIM];
  __shared__ float wv[HDIM];
  int last = N-1, tid = threadIdx.x;
  if (tid < HDIM){
    float acc = b2f(H1[(size_t)last*HPAD + tid]);
    for (int e = rows[last]; e < E; ++e)
      acc += b2f(H1[(size_t)csr[e]*HPAD + tid]);
    Y2[tid] = acc * dinv[last];
  }
  __syncthreads();
  if (tid < HDIM){
    float s = bb2[tid];
    for (int k=0;k<HDIM;k++) s += Y2[k]*Wb2[k*HDIM + tid];
    wv[tid] = fmaxf(s, 0.f);
  }
  __syncthreads();
  if (tid < 128){
    float s = blb[tid];
    for (int c=0;c<HDIM;c++) s += wv[c]*Wlb[c*128 + tid];
    xb[tid] = s;
  }
}

// ================= bilinear score =================
__global__ void score_kernel(const float* __restrict__ xc, const float* __restrict__ W,
                             const float* __restrict__ bias, const float* __restrict__ xm,
                             const float* __restrict__ xb, float* __restrict__ out){
  __shared__ float xd[256];
  __shared__ float u[256];
  int tid = threadIdx.x;
  xd[tid] = (tid < 128) ? xm[tid] : xb[tid-128];
  __syncthreads();
  float s = 0.f;
  for (int j=0;j<256;j++) s += W[(size_t)tid*256 + j]*xd[j];
  u[tid] = s;
  __syncthreads();
  if (tid < B_CLLN){
    float sc = bias[0];
    const float* xr = xc + (size_t)tid*256;
    for (int i=0;i<256;i++) sc += xr[i]*u[i];
    out[tid] = sc;
  }
}

extern "C" void kernel_launch(void* const* d_in, const int* in_sizes, int n_in,
                              void* d_out, int out_size, void* d_ws, size_t ws_size,
                              hipStream_t stream) {
  const float* x_cll = (const float*)d_in[0];
  const float* x_mol = (const float*)d_in[1];
  const float* x_bio = (const float*)d_in[2];
  const int* e_cll = (const int*)d_in[3];
  const int* e_mol = (const int*)d_in[5];
  const int* e_bio = (const int*)d_in[6];
  const float *Wc1=(const float*)d_in[7],  *bc1=(const float*)d_in[8];
  const float *Wc2=(const float*)d_in[9],  *bc2=(const float*)d_in[10];
  const float *Wlc=(const float*)d_in[11], *blc=(const float*)d_in[12];
  const float *Wrel1=(const float*)d_in[13],*brel1=(const float*)d_in[14],*Wroot1=(const float*)d_in[15];
  const float *Wrel2=(const float*)d_in[16],*brel2=(const float*)d_in[17],*Wroot2=(const float*)d_in[18];
  const float *Wlm=(const float*)d_in[19], *blm=(const float*)d_in[20];
  const float *Wb1=(const float*)d_in[21], *bb1=(const float*)d_in[22];
  const float *Wb2=(const float*)d_in[23], *bb2=(const float*)d_in[24];
  const float *Wlb=(const float*)d_in[25], *blb=(const float*)d_in[26];
  const float *Wbl=(const float*)d_in[27], *bias=(const float*)d_in[28];
  float* out = (float*)d_out;

  char* ws = (char*)d_ws;
  size_t o = 0;
  auto alloc = [&](size_t bytes)->char*{
    char* p = ws + o;
    o = (o + bytes + 255) & ~(size_t)255;
    return p;
  };
  u16*   XS    = (u16*)  alloc((size_t)N_CLLN*128*2);
  u16*   Y1    = (u16*)  alloc((size_t)N_CLLN*128*2);
  u16*   BUF1  = (u16*)  alloc((size_t)N_CLLN*HPAD*2);
  u16*   BUF2  = (u16*)  alloc((size_t)N_CLLN*HPAD*2);
  float* dinvC = (float*)alloc((size_t)N_CLLN*4);
  float* dinvB = (float*)alloc((size_t)N_BION*4);
  int*   cntC  = (int*)  alloc((size_t)(2*N_CLLN+2*N_BION)*4);
  int*   curC  = cntC + N_CLLN;
  int*   cntB  = curC + N_CLLN;
  int*   curB  = cntB + N_BION;
  int*   rowC  = (int*)  alloc((size_t)N_CLLN*4);
  int*   csrC  = (int*)  alloc((size_t)E_CLLN*4);
  int*   rowB  = (int*)  alloc((size_t)N_BION*4);
  int*   csrB  = (int*)  alloc((size_t)E_BION*4);
  int*   bsumC = (int*)  alloc(256*4);
  int*   bsumB = (int*)  alloc(256*4);
  float* pooled= (float*)alloc((size_t)B_CLLN*HDIM*4);
  float* xc    = (float*)alloc((size_t)B_CLLN*256*4);
  float* a1    = (float*)alloc((size_t)(N_MOLN*64 + N_MOLN*HDIM + HDIM)*4);
  float* a2    = a1 + N_MOLN*64;
  float* colsum= a2 + N_MOLN*HDIM;
  float* m1    = (float*)alloc((size_t)N_MOLN*HDIM*4);
  float* xm    = (float*)alloc(128*4);
  float* xb    = (float*)alloc(128*4);
  u16* Pc1 = (u16*)alloc((size_t)4*NT*64*8*2);
  u16* Pc2 = (u16*)alloc((size_t)7*NT*64*8*2);
  u16* Pb1 = (u16*)alloc((size_t)4*NT*64*8*2);
  u16* Pb2 = (u16*)alloc((size_t)7*NT*64*8*2);
  if (o > ws_size) return;
  (void)in_sizes; (void)n_in; (void)out_size; (void)Pb2;

  hipMemsetAsync(cntC, 0, (size_t)(2*N_CLLN+2*N_BION)*4, stream);
  hipMemsetAsync(pooled, 0, (size_t)B_CLLN*HDIM*4, stream);
  hipMemsetAsync(a1, 0, (size_t)(N_MOLN*64 + N_MOLN*HDIM + HDIM)*4, stream);

  // pack weights
  pack_w<<<(4*NT*64+255)/256, 256, 0, stream>>>(Wc1, Pc1, 128, 4);
  pack_w<<<(7*NT*64+255)/256, 256, 0, stream>>>(Wc2, Pc2, 200, 7);
  pack_w<<<(4*NT*64+255)/256, 256, 0, stream>>>(Wb1, Pb1, 128, 4);

  // ---- CSR build: cll ----
  const int* srcC = e_cll;  const int* dstC = e_cll + E_CLLN;
  hist_kernel<<<(E_CLLN+255)/256, 256, 0, stream>>>(dstC, cntC, E_CLLN);
  make_dinv<<<(N_CLLN+255)/256, 256, 0, stream>>>(cntC, dinvC, N_CLLN);
  scan1<<<(N_CLLN+1023)/1024, 256, 0, stream>>>(cntC, rowC, bsumC, N_CLLN);
  scan2<<<1, 256, 0, stream>>>(bsumC, (N_CLLN+1023)/1024);
  scan3<<<(N_CLLN+255)/256, 256, 0, stream>>>(rowC, bsumC, N_CLLN);
  csr_scatter<<<(E_CLLN+255)/256, 256, 0, stream>>>(srcC, dstC, rowC, curC, csrC, E_CLLN);
  // ---- CSR build: bio ----
  const int* srcB = e_bio;  const int* dstB = e_bio + E_BION;
  hist_kernel<<<(E_BION+255)/256, 256, 0, stream>>>(dstB, cntB, E_BION);
  make_dinv<<<(N_BION+255)/256, 256, 0, stream>>>(cntB, dinvB, N_BION);
  scan1<<<(N_BION+1023)/1024, 256, 0, stream>>>(cntB, rowB, bsumB, N_BION);
  scan2<<<1, 256, 0, stream>>>(bsumB, (N_BION+1023)/1024);
  scan3<<<(N_BION+255)/256, 256, 0, stream>>>(rowB, bsumB, N_BION);
  csr_scatter<<<(E_BION+255)/256, 256, 0, stream>>>(srcB, dstB, rowB, curB, csrB, E_BION);

  const int wcll = (N_CLLN+3)/4;
  const int wbio = (N_BION+3)/4;
  const int mcll = (N_CLLN+127)/128;
  const int mbio = (N_BION+127)/128;

  // ---- cll branch ----
  prescale128<<<(N_CLLN*16+255)/256, 256, 0, stream>>>(x_cll, dinvC, XS, N_CLLN);
  gather128<<<wcll, 256, 0, stream>>>(XS, dinvC, rowC, csrC, Y1, N_CLLN, E_CLLN);
  gemm_h1<4,128><<<mcll, 256, 0, stream>>>(Y1, Pc1, bc1, dinvC, BUF1, N_CLLN, 128);
  gather256<<<wcll, 256, 0, stream>>>(BUF1, dinvC, rowC, csrC, BUF2, N_CLLN, E_CLLN);
  gemm_pool<7,200><<<mcll, 256, 0, stream>>>(BUF2, Pc2, bc2, pooled, N_CLLN, HPAD);
  xc_kernel<<<B_CLLN, 256, 0, stream>>>(pooled, Wlc, blc, xc);

  // ---- bio branch (reuses big buffers after cll is done with them) ----
  prescale128<<<(N_BION*16+255)/256, 256, 0, stream>>>(x_bio, dinvB, XS, N_BION);
  gather128<<<wbio, 256, 0, stream>>>(XS, dinvB, rowB, csrB, Y1, N_BION, E_BION);
  gemm_h1<4,128><<<mbio, 256, 0, stream>>>(Y1, Pb1, bb1, dinvB, BUF1, N_BION, 128);
  bio_head<<<1, 256, 0, stream>>>(BUF1, dinvB, rowB, csrB, bb2, Wb2, Wlb, blb,
                                  xb, N_BION, E_BION);

  // ---- mol branch ----
  mol_agg<<<(E_MOLN*64+255)/256, 256, 0, stream>>>(x_mol, e_mol, e_mol + E_MOLN, a1, E_MOLN, 64);
  mol_l1<<<(N_MOLN*HDIM+255)/256, 256, 0, stream>>>(x_mol, a1, Wrel1, brel1, Wroot1, m1);
  mol_agg<<<(E_MOLN*HDIM+255)/256, 256, 0, stream>>>(m1, e_mol, e_mol + E_MOLN, a2, E_MOLN, HDIM);
  mol_l2<<<(N_MOLN*HDIM+255)/256, 256, 0, stream>>>(m1, a2, Wrel2, brel2, Wroot2, colsum);
  mol_head<<<1, 128, 0, stream>>>(colsum, Wlm, blm, xm);

  // ---- score ----
  score_kernel<<<1, 256, 0, stream>>>(xc, Wbl, bias, xm, xb, out);
}

// Round 8
// 642.732 us; speedup vs baseline: 1.2107x; 1.0336x over previous
//
#include <hip/hip_runtime.h>

typedef unsigned short u16;
typedef __attribute__((ext_vector_type(8))) short s16x8;
typedef __attribute__((ext_vector_type(4))) float f32x4;
typedef __attribute__((ext_vector_type(4))) unsigned u32x4;
typedef __attribute__((ext_vector_type(2))) unsigned u32x2;

#define N_CLLN 120000
#define B_CLLN 200
#define NPG    600
#define E_CLLN 1200000
#define N_MOLN 64
#define E_MOLN 256
#define N_BION 19000
#define E_BION 600000
#define HDIM   200
#define HPAD   256   // padded row stride (512 B)
#define NT     13    // 13*16 = 208 >= 200 output cols

__device__ __forceinline__ float b2f(u16 u){ return __uint_as_float(((unsigned)u)<<16); }
__device__ __forceinline__ float u2f_lo(unsigned u){ return __uint_as_float(u<<16); }
__device__ __forceinline__ float u2f_hi(unsigned u){ return __uint_as_float(u & 0xFFFF0000u); }
__device__ __forceinline__ u16 f2b(float f){
  unsigned x = __float_as_uint(f);
  return (u16)((x + 0x7fffu + ((x>>16)&1u)) >> 16);
}

// ================= CSR build =================
__global__ void hist_kernel(const int* __restrict__ dst, int* __restrict__ cnt, int E){
  int i = blockIdx.x*blockDim.x + threadIdx.x;
  if (i < E) atomicAdd(&cnt[dst[i]], 1);
}
__global__ void make_dinv(const int* __restrict__ cnt, float* __restrict__ dinv, int N){
  int i = blockIdx.x*blockDim.x + threadIdx.x;
  if (i < N) dinv[i] = rsqrtf((float)cnt[i] + 1.0f);   // +1 self loop
}
__global__ void scan1(const int* __restrict__ cnt, int* __restrict__ rows,
                      int* __restrict__ bsum, int N){
  __shared__ int sh[256];
  int b = blockIdx.x, t = threadIdx.x;
  int base = b*1024 + t*4;
  int v[4]; int s = 0;
#pragma unroll
  for (int i=0;i<4;i++){ int idx = base+i; v[i] = (idx<N)?cnt[idx]:0; s += v[i]; }
  sh[t] = s; __syncthreads();
  for (int off=1; off<256; off<<=1){
    int x = (t>=off)? sh[t-off] : 0; __syncthreads();
    sh[t] += x; __syncthreads();
  }
  int run = (t==0)? 0 : sh[t-1];
#pragma unroll
  for (int i=0;i<4;i++){ int idx = base+i; if (idx<N) rows[idx] = run; run += v[i]; }
  if (t==255) bsum[b] = sh[255];
}
__global__ void scan2(int* __restrict__ bsum, int nb){
  __shared__ int sh[256];
  int t = threadIdx.x;
  sh[t] = (t<nb)? bsum[t] : 0; __syncthreads();
  for (int off=1; off<256; off<<=1){
    int x = (t>=off)? sh[t-off] : 0; __syncthreads();
    sh[t] += x; __syncthreads();
  }
  if (t<nb) bsum[t] = (t==0)? 0 : sh[t-1];
}
__global__ void scan3(int* __restrict__ rows, const int* __restrict__ bsum, int N){
  int i = blockIdx.x*blockDim.x + threadIdx.x;
  if (i<N) rows[i] += bsum[i>>10];
}
__global__ void csr_scatter(const int* __restrict__ src, const int* __restrict__ dst,
                            const int* __restrict__ rows, int* __restrict__ cur,
                            int* __restrict__ csr, int E){
  int e = blockIdx.x*blockDim.x + threadIdx.x;
  if (e >= E) return;
  int d = dst[e];
  int p = atomicAdd(&cur[d], 1);
  csr[rows[d] + p] = src[e];
}

// ===== prescale: X'[r] = dinv[r]*X[r], fp32[N,128] -> bf16[N,128] =====
__global__ void prescale128(const float* __restrict__ x, const float* __restrict__ dinv,
                            u16* __restrict__ out, int N){
  int idx = blockIdx.x*blockDim.x + threadIdx.x;
  if (idx >= N*16) return;
  int r = idx >> 4, c8 = (idx & 15) << 3;
  float dv = dinv[r];
  const float* p = x + (size_t)r*128 + c8;
  f32x4 v0 = *(const f32x4*)p;
  f32x4 v1 = *(const f32x4*)(p+4);
  u32x4 w;
  w[0] = (unsigned)f2b(v0[0]*dv) | ((unsigned)f2b(v0[1]*dv)<<16);
  w[1] = (unsigned)f2b(v0[2]*dv) | ((unsigned)f2b(v0[3]*dv)<<16);
  w[2] = (unsigned)f2b(v1[0]*dv) | ((unsigned)f2b(v1[1]*dv)<<16);
  w[3] = (unsigned)f2b(v1[2]*dv) | ((unsigned)f2b(v1[3]*dv)<<16);
  *(u32x4*)(out + (size_t)r*128 + c8) = w;
}

// ===== paired gather over 128-col bf16 rows (256B): two rows at a time =====
// Y[d] = dinv[d]*(X'[d] + sum X'[s]);  lanes 0-31 handle even idx, 32-63 odd idx
__global__ __launch_bounds__(256) void gather128(
    const u16* __restrict__ X, const float* __restrict__ dinv,
    const int* __restrict__ rows, const int* __restrict__ csr,
    u16* __restrict__ Y, int N, int E)
{
  int wid = (blockIdx.x*blockDim.x + threadIdx.x) >> 6;
  int l = threadIdx.x & 63;
  if (wid >= N) return;
  int half = l >> 5, lh = l & 31;
  float dv = dinv[wid];
  int e0 = rows[wid];
  int e1 = (wid+1 < N) ? rows[wid+1] : E;
  const unsigned* base = (const unsigned*)X;
  float a0=0.f, a1=0.f, a2=0.f, a3=0.f;
  if (half == 0){
    u32x2 sv = *((const u32x2*)(base + (size_t)wid*64) + lh);
    a0 = u2f_lo(sv[0]); a1 = u2f_hi(sv[0]);
    a2 = u2f_lo(sv[1]); a3 = u2f_hi(sv[1]);
  }
  for (int b0 = e0; b0 < e1; b0 += 64){
    int n = e1 - b0;
    int cnt = n < 64 ? n : 64;
    int myv = (l < cnt) ? csr[b0 + l] : 0;
    int i = 0;
    for (; i + 15 < cnt; i += 16){
      u32x2 P[8];
#pragma unroll
      for (int u=0;u<8;u++){
        int s = __shfl(myv, i + 2*u + half);
        P[u] = *((const u32x2*)(base + (size_t)s*64) + lh);
      }
#pragma unroll
      for (int u=0;u<8;u++){
        a0 += u2f_lo(P[u][0]); a1 += u2f_hi(P[u][0]);
        a2 += u2f_lo(P[u][1]); a3 += u2f_hi(P[u][1]);
      }
    }
    for (; i < cnt; i += 2){
      int idx = i + half;
      int cidx = idx < cnt ? idx : cnt-1;
      int s = __shfl(myv, cidx);
      u32x2 P = *((const u32x2*)(base + (size_t)s*64) + lh);
      if (idx < cnt){
        a0 += u2f_lo(P[0]); a1 += u2f_hi(P[0]);
        a2 += u2f_lo(P[1]); a3 += u2f_hi(P[1]);
      }
    }
  }
  a0 += __shfl_xor(a0, 32); a1 += __shfl_xor(a1, 32);
  a2 += __shfl_xor(a2, 32); a3 += __shfl_xor(a3, 32);
  if (half == 0){
    u32x2 wv;
    wv[0] = (unsigned)f2b(a0*dv) | ((unsigned)f2b(a1*dv) << 16);
    wv[1] = (unsigned)f2b(a2*dv) | ((unsigned)f2b(a3*dv) << 16);
    *((u32x2*)((unsigned*)Y + (size_t)wid*64) + lh) = wv;
  }
}

// ===== paired gather over padded 256-col bf16 rows (512B): two rows at a time =====
__global__ __launch_bounds__(256) void gather256(
    const u16* __restrict__ t, const float* __restrict__ dinv,
    const int* __restrict__ rows, const int* __restrict__ csr,
    u16* __restrict__ out, int N, int E)
{
  int wid = (blockIdx.x*blockDim.x + threadIdx.x) >> 6;
  int l = threadIdx.x & 63;
  if (wid >= N) return;
  int half = l >> 5, lh = l & 31;
  float dv = dinv[wid];
  int e0 = rows[wid];
  int e1 = (wid+1 < N) ? rows[wid+1] : E;
  const unsigned* base = (const unsigned*)t;
  float a0=0.f,a1=0.f,a2=0.f,a3=0.f,a4=0.f,a5=0.f,a6=0.f,a7=0.f;
  if (half == 0){
    u32x4 sv = *((const u32x4*)(base + (size_t)wid*128) + lh);
    a0 = u2f_lo(sv[0]); a1 = u2f_hi(sv[0]);
    a2 = u2f_lo(sv[1]); a3 = u2f_hi(sv[1]);
    a4 = u2f_lo(sv[2]); a5 = u2f_hi(sv[2]);
    a6 = u2f_lo(sv[3]); a7 = u2f_hi(sv[3]);
  }
  for (int b0 = e0; b0 < e1; b0 += 64){
    int n = e1 - b0;
    int cnt = n < 64 ? n : 64;
    int myv = (l < cnt) ? csr[b0 + l] : 0;
    int i = 0;
    for (; i + 15 < cnt; i += 16){
      u32x4 P[8];
#pragma unroll
      for (int u=0;u<8;u++){
        int s = __shfl(myv, i + 2*u + half);
        P[u] = *((const u32x4*)(base + (size_t)s*128) + lh);
      }
#pragma unroll
      for (int u=0;u<8;u++){
        a0 += u2f_lo(P[u][0]); a1 += u2f_hi(P[u][0]);
        a2 += u2f_lo(P[u][1]); a3 += u2f_hi(P[u][1]);
        a4 += u2f_lo(P[u][2]); a5 += u2f_hi(P[u][2]);
        a6 += u2f_lo(P[u][3]); a7 += u2f_hi(P[u][3]);
      }
    }
    for (; i < cnt; i += 2){
      int idx = i + half;
      int cidx = idx < cnt ? idx : cnt-1;
      int s = __shfl(myv, cidx);
      u32x4 P = *((const u32x4*)(base + (size_t)s*128) + lh);
      if (idx < cnt){
        a0 += u2f_lo(P[0]); a1 += u2f_hi(P[0]);
        a2 += u2f_lo(P[1]); a3 += u2f_hi(P[1]);
        a4 += u2f_lo(P[2]); a5 += u2f_hi(P[2]);
        a6 += u2f_lo(P[3]); a7 += u2f_hi(P[3]);
      }
    }
  }
  a0 += __shfl_xor(a0, 32); a1 += __shfl_xor(a1, 32);
  a2 += __shfl_xor(a2, 32); a3 += __shfl_xor(a3, 32);
  a4 += __shfl_xor(a4, 32); a5 += __shfl_xor(a5, 32);
  a6 += __shfl_xor(a6, 32); a7 += __shfl_xor(a7, 32);
  if (half == 0){
    u32x4 wv = {0,0,0,0};
    if (lh < 25){   // cols 8*lh .. 8*lh+7 < 200
      wv[0] = (unsigned)f2b(a0*dv) | ((unsigned)f2b(a1*dv) << 16);
      wv[1] = (unsigned)f2b(a2*dv) | ((unsigned)f2b(a3*dv) << 16);
      wv[2] = (unsigned)f2b(a4*dv) | ((unsigned)f2b(a5*dv) << 16);
      wv[3] = (unsigned)f2b(a6*dv) | ((unsigned)f2b(a7*dv) << 16);
    }
    *((u32x4*)((unsigned*)out + (size_t)wid*128) + lh) = wv;
  }
}

// ================= B-operand pre-pack (fp32 W -> bf16 MFMA fragment order) =================
__global__ void pack_w(const float* __restrict__ W, u16* __restrict__ Bp, int K, int Ksteps){
  int idx = blockIdx.x*blockDim.x + threadIdx.x;
  int total = Ksteps*NT*64;
  if (idx >= total) return;
  int l  = idx & 63;
  int nt = (idx >> 6) % NT;
  int kk = idx / (64*NT);
  int n  = nt*16 + (l & 15);
  int k0 = kk*32 + (l>>4)*8;
  u16 v[8];
#pragma unroll
  for (int e=0;e<8;e++){
    int k = k0 + e;
    v[e] = (k < K && n < HDIM) ? f2b(W[(size_t)k*HDIM + n]) : (u16)0;
  }
#pragma unroll
  for (int e=0;e<8;e++) Bp[(size_t)idx*8 + e] = v[e];
}

// ===== GEMM core: 128 rows/block, 4 waves, 2 A-frags per wave, compile-time K =====
template<int KSTEPS, int KACT>
__global__ __launch_bounds__(256) void gemm_h1(
    const u16* __restrict__ A, const u16* __restrict__ Bp,
    const float* __restrict__ bias, const float* __restrict__ dinv,
    u16* __restrict__ Out, int M, int Astride)
{
  const int w  = threadIdx.x >> 6;
  const int l  = threadIdx.x & 63;
  const int lm = l & 15;
  const int kg = l >> 4;
  const int base = blockIdx.x*128;
  int r0 = base + w*16 + lm;
  int r1 = r0 + 64;
  const u16* A0 = A + (size_t)(r0 < M ? r0 : 0) * Astride;
  const u16* A1 = A + (size_t)(r1 < M ? r1 : 0) * Astride;
  f32x4 acc[2][NT] = {};
  const s16x8 az = {0,0,0,0,0,0,0,0};
#pragma unroll
  for (int kk=0; kk<KSTEPS; ++kk){
    int k0 = kk*32 + kg*8;
    s16x8 a0 = (k0 < KACT) ? *(const s16x8*)(A0 + k0) : az;
    s16x8 a1 = (k0 < KACT) ? *(const s16x8*)(A1 + k0) : az;
    const u16* bp = Bp + ((size_t)kk*NT*64 + l)*8;
#pragma unroll
    for (int t=0;t<NT;t++){
      s16x8 b = *(const s16x8*)(bp + t*512);
      acc[0][t] = __builtin_amdgcn_mfma_f32_16x16x32_bf16(a0, b, acc[0][t], 0, 0, 0);
      acc[1][t] = __builtin_amdgcn_mfma_f32_16x16x32_bf16(a1, b, acc[1][t], 0, 0, 0);
    }
  }
#pragma unroll
  for (int m=0;m<2;m++){
    int orow = base + m*64 + w*16 + kg*4;   // C/D: col=lane&15, row=(lane>>4)*4+j
    float scj[4];
#pragma unroll
    for (int j=0;j<4;j++){ int r = orow + j; scj[j] = (r < M) ? dinv[r] : 0.f; }
#pragma unroll
    for (int t=0;t<NT;t++){
      int c = t*16 + lm;
#pragma unroll
      for (int j=0;j<4;j++){
        int r = orow + j;
        if (r < M){
          float v = 0.f;
          if (c < HDIM) v = fmaxf(acc[m][t][j] + bias[c], 0.f) * scj[j];
          Out[(size_t)r*HPAD + c] = f2b(v);
        }
      }
    }
  }
}

// ===== GEMM + fused mean-pool epilogue: per-wave LDS slices, no LDS atomics =====
template<int KSTEPS, int KACT>
__global__ __launch_bounds__(256) void gemm_pool(
    const u16* __restrict__ A, const u16* __restrict__ Bp,
    const float* __restrict__ bias, float* __restrict__ pooled,
    int M, int Astride)
{
  __shared__ float ps[4][2][HPAD];
  for (int i = threadIdx.x; i < 4*2*HPAD; i += 256) ((float*)ps)[i] = 0.f;
  __syncthreads();
  const int w  = threadIdx.x >> 6;
  const int l  = threadIdx.x & 63;
  const int lm = l & 15;
  const int kg = l >> 4;
  const int base = blockIdx.x*128;
  int r0 = base + w*16 + lm;
  int r1 = r0 + 64;
  const u16* A0 = A + (size_t)(r0 < M ? r0 : 0) * Astride;
  const u16* A1 = A + (size_t)(r1 < M ? r1 : 0) * Astride;
  f32x4 acc[2][NT] = {};
  const s16x8 az = {0,0,0,0,0,0,0,0};
#pragma unroll
  for (int kk=0; kk<KSTEPS; ++kk){
    int k0 = kk*32 + kg*8;
    s16x8 a0 = (k0 < KACT) ? *(const s16x8*)(A0 + k0) : az;
    s16x8 a1 = (k0 < KACT) ? *(const s16x8*)(A1 + k0) : az;
    const u16* bp = Bp + ((size_t)kk*NT*64 + l)*8;
#pragma unroll
    for (int t=0;t<NT;t++){
      s16x8 b = *(const s16x8*)(bp + t*512);
      acc[0][t] = __builtin_amdgcn_mfma_f32_16x16x32_bf16(a0, b, acc[0][t], 0, 0, 0);
      acc[1][t] = __builtin_amdgcn_mfma_f32_16x16x32_bf16(a1, b, acc[1][t], 0, 0, 0);
    }
  }
  const int g0 = base / NPG;
#pragma unroll
  for (int m=0;m<2;m++){
    int R0 = base + m*64 + w*16;   // wave-uniform fragment start
    bool uni = (R0 + 15 < M) && ((R0/NPG) == ((R0+15)/NPG));
    int slotU = (R0/NPG) - g0;
#pragma unroll
    for (int t=0;t<NT;t++){
      int c = t*16 + lm;
      if (c < HDIM){
        float v0 = fmaxf(acc[m][t][0] + bias[c], 0.f);
        float v1 = fmaxf(acc[m][t][1] + bias[c], 0.f);
        float v2 = fmaxf(acc[m][t][2] + bias[c], 0.f);
        float v3 = fmaxf(acc[m][t][3] + bias[c], 0.f);
        if (uni){
          float s = v0+v1+v2+v3;
          s += __shfl_xor(s, 16);
          s += __shfl_xor(s, 32);
          if (kg == 0) ps[w][slotU][c] += s;
        } else {
          float s0 = 0.f, s1 = 0.f;
          float vv[4] = {v0,v1,v2,v3};
#pragma unroll
          for (int j=0;j<4;j++){
            int r = R0 + kg*4 + j;
            if (r < M){
              if ((r/NPG) - g0 == 0) s0 += vv[j]; else s1 += vv[j];
            }
          }
          s0 += __shfl_xor(s0, 16); s0 += __shfl_xor(s0, 32);
          s1 += __shfl_xor(s1, 16); s1 += __shfl_xor(s1, 32);
          if (kg == 0){ ps[w][0][c] += s0; ps[w][1][c] += s1; }
        }
      }
    }
  }
  __syncthreads();
  for (int i = threadIdx.x; i < 2*HDIM; i += 256){
    int slot = i / HDIM, c = i % HDIM;
    float s = ps[0][slot][c] + ps[1][slot][c] + ps[2][slot][c] + ps[3][slot][c];
    int g = g0 + slot;
    if (g < B_CLLN && s != 0.f) unsafeAtomicAdd(&pooled[g*HDIM + c], s);
  }
}

// ================= xc = pooled/NPG @ Wlc + blc =================
__global__ void xc_kernel(const float* __restrict__ pooled, const float* __restrict__ Wlc,
                          const float* __restrict__ blc, float* __restrict__ xc){
  __shared__ float p[HDIM];
  int b = blockIdx.x, j = threadIdx.x;
  if (j < HDIM) p[j] = pooled[b*HDIM + j] * (1.0f/NPG);
  __syncthreads();
  float s = blc[j];
  for (int k=0;k<HDIM;k++) s += p[k]*Wlc[(size_t)k*256 + j];
  xc[(size_t)b*256 + j] = s;
}

// ================= mol branch (all fp32) =================
__global__ void mol_agg(const float* __restrict__ x, const int* __restrict__ src,
                        const int* __restrict__ dst, float* __restrict__ a, int E, int F){
  int idx = blockIdx.x*blockDim.x + threadIdx.x;
  if (idx >= E*F) return;
  int e = idx / F, f = idx % F;
  unsafeAtomicAdd(&a[dst[e]*F + f], x[(size_t)src[e]*F + f]);
}
__global__ void mol_l1(const float* __restrict__ x, const float* __restrict__ a1,
                       const float* __restrict__ Wrel, const float* __restrict__ brel,
                       const float* __restrict__ Wroot, float* __restrict__ m1){
  int idx = blockIdx.x*blockDim.x + threadIdx.x;
  if (idx >= N_MOLN*HDIM) return;
  int i = idx / HDIM, c = idx % HDIM;
  float s = brel[c];
  for (int k=0;k<64;k++){
    s += a1[i*64+k]*Wrel[k*HDIM+c];
    s += x[i*64+k]*Wroot[k*HDIM+c];
  }
  m1[idx] = fmaxf(s, 0.f);
}
__global__ void mol_l2(const float* __restrict__ m1, const float* __restrict__ a2,
                       const float* __restrict__ Wrel2, const float* __restrict__ brel2,
                       const float* __restrict__ Wroot2, float* __restrict__ colsum){
  int idx = blockIdx.x*blockDim.x + threadIdx.x;
  if (idx >= N_MOLN*HDIM) return;
  int i = idx / HDIM, c = idx % HDIM;
  float s = brel2[c];
  for (int k=0;k<HDIM;k++){
    s += a2[i*HDIM+k]*Wrel2[k*HDIM+c] + m1[i*HDIM+k]*Wroot2[k*HDIM+c];
  }
  s = fmaxf(s, 0.f);
  unsafeAtomicAdd(&colsum[c], s*(1.0f/N_MOLN));
}
__global__ void mol_head(const float* __restrict__ colsum, const float* __restrict__ Wlm,
                         const float* __restrict__ blm, float* __restrict__ xm){
  int j = threadIdx.x;
  if (j >= 128) return;
  float s = blm[j];
  for (int c=0;c<HDIM;c++) s += colsum[c]*Wlm[c*128+j];
  xm[j] = s;
}

// ===== bio tail: aggregate-first for last node only, then Wb2+relu, then Wlb =====
__global__ void bio_head(const u16* __restrict__ H1, const float* __restrict__ dinv,
                         const int* __restrict__ rows, const int* __restrict__ csr,
                         const float* __restrict__ bb2, const float* __restrict__ Wb2,
                         const float* __restrict__ Wlb, const float* __restrict__ blb,
                         float* __restrict__ xb, int N, int E){
  __shared__ float Y2[HDIM];
  __shared__ float wv[HDIM];
  int last = N-1, tid = threadIdx.x;
  if (tid < HDIM){
    float acc = b2f(H1[(size_t)last*HPAD + tid]);
    for (int e = rows[last]; e < E; ++e)
      acc += b2f(H1[(size_t)csr[e]*HPAD + tid]);
    Y2[tid] = acc * dinv[last];
  }
  __syncthreads();
  if (tid < HDIM){
    float s = bb2[tid];
    for (int k=0;k<HDIM;k++) s += Y2[k]*Wb2[k*HDIM + tid];
    wv[tid] = fmaxf(s, 0.f);
  }
  __syncthreads();
  if (tid < 128){
    float s = blb[tid];
    for (int c=0;c<HDIM;c++) s += wv[c]*Wlb[c*128 + tid];
    xb[tid] = s;
  }
}

// ================= bilinear score =================
__global__ void score_kernel(const float* __restrict__ xc, const float* __restrict__ W,
                             const float* __restrict__ bias, const float* __restrict__ xm,
                             const float* __restrict__ xb, float* __restrict__ out){
  __shared__ float xd[256];
  __shared__ float u[256];
  int tid = threadIdx.x;
  xd[tid] = (tid < 128) ? xm[tid] : xb[tid-128];
  __syncthreads();
  float s = 0.f;
  for (int j=0;j<256;j++) s += W[(size_t)tid*256 + j]*xd[j];
  u[tid] = s;
  __syncthreads();
  if (tid < B_CLLN){
    float sc = bias[0];
    const float* xr = xc + (size_t)tid*256;
    for (int i=0;i<256;i++) sc += xr[i]*u[i];
    out[tid] = sc;
  }
}

extern "C" void kernel_launch(void* const* d_in, const int* in_sizes, int n_in,
                              void* d_out, int out_size, void* d_ws, size_t ws_size,
                              hipStream_t stream) {
  const float* x_cll = (const float*)d_in[0];
  const float* x_mol = (const float*)d_in[1];
  const float* x_bio = (const float*)d_in[2];
  const int* e_cll = (const int*)d_in[3];
  const int* e_mol = (const int*)d_in[5];
  const int* e_bio = (const int*)d_in[6];
  const float *Wc1=(const float*)d_in[7],  *bc1=(const float*)d_in[8];
  const float *Wc2=(const float*)d_in[9],  *bc2=(const float*)d_in[10];
  const float *Wlc=(const float*)d_in[11], *blc=(const float*)d_in[12];
  const float *Wrel1=(const float*)d_in[13],*brel1=(const float*)d_in[14],*Wroot1=(const float*)d_in[15];
  const float *Wrel2=(const float*)d_in[16],*brel2=(const float*)d_in[17],*Wroot2=(const float*)d_in[18];
  const float *Wlm=(const float*)d_in[19], *blm=(const float*)d_in[20];
  const float *Wb1=(const float*)d_in[21], *bb1=(const float*)d_in[22];
  const float *Wb2=(const float*)d_in[23], *bb2=(const float*)d_in[24];
  const float *Wlb=(const float*)d_in[25], *blb=(const float*)d_in[26];
  const float *Wbl=(const float*)d_in[27], *bias=(const float*)d_in[28];
  float* out = (float*)d_out;

  char* ws = (char*)d_ws;
  size_t o = 0;
  auto alloc = [&](size_t bytes)->char*{
    char* p = ws + o;
    o = (o + bytes + 255) & ~(size_t)255;
    return p;
  };
  u16*   XS    = (u16*)  alloc((size_t)N_CLLN*128*2);
  u16*   Y1    = (u16*)  alloc((size_t)N_CLLN*128*2);
  u16*   BUF1  = (u16*)  alloc((size_t)N_CLLN*HPAD*2);
  u16*   BUF2  = (u16*)  alloc((size_t)N_CLLN*HPAD*2);
  float* dinvC = (float*)alloc((size_t)N_CLLN*4);
  float* dinvB = (float*)alloc((size_t)N_BION*4);
  int*   cntC  = (int*)  alloc((size_t)(2*N_CLLN+2*N_BION)*4);
  int*   curC  = cntC + N_CLLN;
  int*   cntB  = curC + N_CLLN;
  int*   curB  = cntB + N_BION;
  int*   rowC  = (int*)  alloc((size_t)N_CLLN*4);
  int*   csrC  = (int*)  alloc((size_t)E_CLLN*4);
  int*   rowB  = (int*)  alloc((size_t)N_BION*4);
  int*   csrB  = (int*)  alloc((size_t)E_BION*4);
  int*   bsumC = (int*)  alloc(256*4);
  int*   bsumB = (int*)  alloc(256*4);
  float* pooled= (float*)alloc((size_t)B_CLLN*HDIM*4);
  float* xc    = (float*)alloc((size_t)B_CLLN*256*4);
  float* a1    = (float*)alloc((size_t)(N_MOLN*64 + N_MOLN*HDIM + HDIM)*4);
  float* a2    = a1 + N_MOLN*64;
  float* colsum= a2 + N_MOLN*HDIM;
  float* m1    = (float*)alloc((size_t)N_MOLN*HDIM*4);
  float* xm    = (float*)alloc(128*4);
  float* xb    = (float*)alloc(128*4);
  u16* Pc1 = (u16*)alloc((size_t)4*NT*64*8*2);
  u16* Pc2 = (u16*)alloc((size_t)7*NT*64*8*2);
  u16* Pb1 = (u16*)alloc((size_t)4*NT*64*8*2);
  if (o > ws_size) return;
  (void)in_sizes; (void)n_in; (void)out_size;

  hipMemsetAsync(cntC, 0, (size_t)(2*N_CLLN+2*N_BION)*4, stream);
  hipMemsetAsync(pooled, 0, (size_t)B_CLLN*HDIM*4, stream);
  hipMemsetAsync(a1, 0, (size_t)(N_MOLN*64 + N_MOLN*HDIM + HDIM)*4, stream);

  // pack weights
  pack_w<<<(4*NT*64+255)/256, 256, 0, stream>>>(Wc1, Pc1, 128, 4);
  pack_w<<<(7*NT*64+255)/256, 256, 0, stream>>>(Wc2, Pc2, 200, 7);
  pack_w<<<(4*NT*64+255)/256, 256, 0, stream>>>(Wb1, Pb1, 128, 4);

  // ---- CSR build: cll ----
  const int* srcC = e_cll;  const int* dstC = e_cll + E_CLLN;
  hist_kernel<<<(E_CLLN+255)/256, 256, 0, stream>>>(dstC, cntC, E_CLLN);
  make_dinv<<<(N_CLLN+255)/256, 256, 0, stream>>>(cntC, dinvC, N_CLLN);
  scan1<<<(N_CLLN+1023)/1024, 256, 0, stream>>>(cntC, rowC, bsumC, N_CLLN);
  scan2<<<1, 256, 0, stream>>>(bsumC, (N_CLLN+1023)/1024);
  scan3<<<(N_CLLN+255)/256, 256, 0, stream>>>(rowC, bsumC, N_CLLN);
  csr_scatter<<<(E_CLLN+255)/256, 256, 0, stream>>>(srcC, dstC, rowC, curC, csrC, E_CLLN);
  // ---- CSR build: bio ----
  const int* srcB = e_bio;  const int* dstB = e_bio + E_BION;
  hist_kernel<<<(E_BION+255)/256, 256, 0, stream>>>(dstB, cntB, E_BION);
  make_dinv<<<(N_BION+255)/256, 256, 0, stream>>>(cntB, dinvB, N_BION);
  scan1<<<(N_BION+1023)/1024, 256, 0, stream>>>(cntB, rowB, bsumB, N_BION);
  scan2<<<1, 256, 0, stream>>>(bsumB, (N_BION+1023)/1024);
  scan3<<<(N_BION+255)/256, 256, 0, stream>>>(rowB, bsumB, N_BION);
  csr_scatter<<<(E_BION+255)/256, 256, 0, stream>>>(srcB, dstB, rowB, curB, csrB, E_BION);

  const int wcll = (N_CLLN+3)/4;
  const int wbio = (N_BION+3)/4;
  const int mcll = (N_CLLN+127)/128;
  const int mbio = (N_BION+127)/128;

  // ---- cll branch ----
  prescale128<<<(N_CLLN*16+255)/256, 256, 0, stream>>>(x_cll, dinvC, XS, N_CLLN);
  gather128<<<wcll, 256, 0, stream>>>(XS, dinvC, rowC, csrC, Y1, N_CLLN, E_CLLN);
  gemm_h1<4,128><<<mcll, 256, 0, stream>>>(Y1, Pc1, bc1, dinvC, BUF1, N_CLLN, 128);
  gather256<<<wcll, 256, 0, stream>>>(BUF1, dinvC, rowC, csrC, BUF2, N_CLLN, E_CLLN);
  gemm_pool<7,200><<<mcll, 256, 0, stream>>>(BUF2, Pc2, bc2, pooled, N_CLLN, HPAD);
  xc_kernel<<<B_CLLN, 256, 0, stream>>>(pooled, Wlc, blc, xc);

  // ---- bio branch (reuses big buffers after cll is done with them) ----
  prescale128<<<(N_BION*16+255)/256, 256, 0, stream>>>(x_bio, dinvB, XS, N_BION);
  gather128<<<wbio, 256, 0, stream>>>(XS, dinvB, rowB, csrB, Y1, N_BION, E_BION);
  gemm_h1<4,128><<<mbio, 256, 0, stream>>>(Y1, Pb1, bb1, dinvB, BUF1, N_BION, 128);
  bio_head<<<1, 256, 0, stream>>>(BUF1, dinvB, rowB, csrB, bb2, Wb2, Wlb, blb,
                                  xb, N_BION, E_BION);

  // ---- mol branch ----
  mol_agg<<<(E_MOLN*64+255)/256, 256, 0, stream>>>(x_mol, e_mol, e_mol + E_MOLN, a1, E_MOLN, 64);
  mol_l1<<<(N_MOLN*HDIM+255)/256, 256, 0, stream>>>(x_mol, a1, Wrel1, brel1, Wroot1, m1);
  mol_agg<<<(E_MOLN*HDIM+255)/256, 256, 0, stream>>>(m1, e_mol, e_mol + E_MOLN, a2, E_MOLN, HDIM);
  mol_l2<<<(N_MOLN*HDIM+255)/256, 256, 0, stream>>>(m1, a2, Wrel2, brel2, Wroot2, colsum);
  mol_head<<<1, 128, 0, stream>>>(colsum, Wlm, blm, xm);

  // ---- score ----
  score_kernel<<<1, 256, 0, stream>>>(xc, Wbl, bias, xm, xb, out);
}